// Round 10
// baseline (3308.319 us; speedup 1.0000x reference)
//
#include <hip/hip_runtime.h>
#include <math.h>

#define Bq 512
#define Tq 128
#define Fq 64
#define Uq 1024
#define OSTEPS 24
#define NKC16 68

typedef __bf16 bf16x8 __attribute__((ext_vector_type(8)));
typedef __bf16 bf16x4 __attribute__((ext_vector_type(4)));
typedef __bf16 bf16x2 __attribute__((ext_vector_type(2)));
typedef float f32x16 __attribute__((ext_vector_type(16)));
typedef float f32x4 __attribute__((ext_vector_type(4)));
typedef float f32x2 __attribute__((ext_vector_type(2)));

__device__ __forceinline__ float sigmoidf_(float x) {
    return 1.0f / (1.0f + __expf(-x));
}
__device__ __forceinline__ float tanhf_(float x) {
    return 2.0f / (1.0f + __expf(-2.0f * x)) - 1.0f;
}

#define MFMA(a, b, c) __builtin_amdgcn_mfma_f32_32x32x16_bf16(a, b, c, 0, 0, 0)

#define GLL(gp, lp) __builtin_amdgcn_global_load_lds(                         \
    (const __attribute__((address_space(1))) void*)(gp),                      \
    (__attribute__((address_space(3))) void*)(lp), 16, 0, 0)

// counted-vmcnt barrier: LDS ops drained, up to N global loads stay in flight
#define BARV(N) do {                                                          \
    asm volatile("s_waitcnt vmcnt(" #N ") lgkmcnt(0)" ::: "memory");          \
    __builtin_amdgcn_s_barrier();                                             \
} while (0)
#define BARL() do {                                                           \
    asm volatile("s_waitcnt lgkmcnt(0)" ::: "memory");                        \
    __builtin_amdgcn_s_barrier();                                             \
} while (0)

// ---------------------------------------------------------------------------
// Pack Wh [1024][4096] + Wx [64][4096] (fp32, z-col = g*1024+u) into B-fragment
// order for v_mfma_f32_32x32x16_bf16, split hi/lo bf16. (verified r2-r8)
// ---------------------------------------------------------------------------
__global__ __launch_bounds__(256)
void pack_w(const float* __restrict__ Wh, const float* __restrict__ Wx,
            bf16x8* __restrict__ BpH, bf16x8* __restrict__ BpL)
{
    long id = (long)blockIdx.x * 256 + threadIdx.x;   // 128*68*64 slots
    int lane = (int)(id & 63);
    long rest = id >> 6;
    int kc16 = (int)(rest % NKC16);
    int gcol = (int)(rest / NKC16);                   // 0..127
    int col = (gcol >> 5) * Uq + (gcol & 31) * 32 + (lane & 31);
    int k0 = kc16 * 16 + (lane >> 5) * 8;
    bf16x8 hv, lv;
#pragma unroll
    for (int j = 0; j < 8; ++j) {
        int k = k0 + j;
        float v = (k < Uq) ? Wh[(size_t)k * (4 * Uq) + col]
                           : Wx[(size_t)(k - Uq) * (4 * Uq) + col];
        __bf16 h_ = (__bf16)v;
        hv[j] = h_;
        lv[j] = (__bf16)(v - (float)h_);
    }
    BpH[id] = hv;
    BpL[id] = lv;
}

// ---------------------------------------------------------------------------
// Fused LSTM step. Grid 512 = 16 bm x 32 bu -> 2 blocks/CU (TLP overlap).
// Block: 32 rows x 32 units, 512 thr = 8 waves; wave = (gate g = w&3, K-half
// kh = w>>2; per chunk handles kc16 = 4i + 2kh + {0,1}).
// A staged via global_load_lds (3-buffer rotation, 2 ahead, 1 GLL/wave/chunk),
// B frags in 3-slot register rotation (2 ahead), counted-vmcnt barriers.
// h stored in MFMA A-fragment layout (r7-verified):
//   bf16x8 index = (size_t)mt*8192 + kc*128 + pl*64 + lane
//   (mt = row/32 0..15, kc = k/16 0..63, pl = 0 hi / 1 lo).
// LDS: buf b (0..2 h, 3 x) at b*8192; slot (kco,pl) at (kco*2+pl)*1024.
// zsd f32[2][4][32][36] (36,864 B) unions the bufs after the K loop.
// ---------------------------------------------------------------------------
__global__ __launch_bounds__(512, 4)
void lstm_step(const bf16x8* __restrict__ aph,   // h frags (read)
               const float* __restrict__ xraw,   // warmup x: inputs + t*64
               const bf16x8* __restrict__ xdec8, // decode x frags
               int use_frag_x,
               const bf16x8* __restrict__ BpH,
               const bf16x8* __restrict__ BpL,
               const float* __restrict__ bias,   // [4096]
               bf16x8* __restrict__ apw,         // h frags (write)
               float* __restrict__ c_st)         // [512][1024] fp32 in/out
{
    __shared__ __align__(16) char smem[36864];
    float (*zsd)[4][32][36] = (float (*)[4][32][36])smem;

    const int tid = threadIdx.x;
    const int l   = tid & 63;
    const int w   = tid >> 6;
    const int g   = w & 3;          // gate
    const int kh  = w >> 2;         // K-half
    const int bm  = (int)blockIdx.x >> 5;   // 0..15
    const int bu  = (int)blockIdx.x & 31;
    const int row0 = bm * 32;

    // staging role: wave w stages slot (skc = w>>1, spl = w&1), 1 GLL/chunk
    const int skc = w >> 1;
    const int spl = w & 1;
    const bf16x8* asrc = aph + (size_t)bm * 8192 + (size_t)skc * 128 + spl * 64 + l;
    const int dslot = (skc * 2 + spl) * 1024;

    // B fragment base pointers (per-lane)
    const bf16x8* bhp = BpH + (size_t)(g * 32 + bu) * NKC16 * 64 + l;
    const bf16x8* blp = BpL + (size_t)(g * 32 + bu) * NKC16 * 64 + l;

#define STAGE_H(c, b) GLL(asrc + (size_t)(4 * (c)) * 128, smem + (b) * 8192 + dslot)

#define LOADB(s, c) do {                                                       \
    Bh[s][0] = bhp[(size_t)(4 * (c) + 2 * kh + 0) * 64];                       \
    Bl[s][0] = blp[(size_t)(4 * (c) + 2 * kh + 0) * 64];                       \
    Bh[s][1] = bhp[(size_t)(4 * (c) + 2 * kh + 1) * 64];                       \
    Bl[s][1] = blp[(size_t)(4 * (c) + 2 * kh + 1) * 64];                       \
} while (0)

#define COMPUTE(b, s) do {                                                     \
    const char* bb_ = smem + (b) * 8192;                                       \
    bf16x8 ah0_ = *(const bf16x8*)(bb_ + ((2 * kh + 0) * 2 + 0) * 1024 + l * 16); \
    bf16x8 al0_ = *(const bf16x8*)(bb_ + ((2 * kh + 0) * 2 + 1) * 1024 + l * 16); \
    bf16x8 ah1_ = *(const bf16x8*)(bb_ + ((2 * kh + 1) * 2 + 0) * 1024 + l * 16); \
    bf16x8 al1_ = *(const bf16x8*)(bb_ + ((2 * kh + 1) * 2 + 1) * 1024 + l * 16); \
    __builtin_amdgcn_s_setprio(1);                                             \
    acc = MFMA(ah0_, Bh[s][0], acc);                                           \
    acc = MFMA(al0_, Bh[s][0], acc);                                           \
    acc = MFMA(ah0_, Bl[s][0], acc);                                           \
    acc = MFMA(ah1_, Bh[s][1], acc);                                           \
    acc = MFMA(al1_, Bh[s][1], acc);                                           \
    acc = MFMA(ah1_, Bl[s][1], acc);                                           \
    __builtin_amdgcn_s_setprio(0);                                             \
} while (0)

    f32x16 acc;
#pragma unroll
    for (int i = 0; i < 16; ++i) acc[i] = 0.0f;
    bf16x8 Bh[3][2], Bl[3][2];

    // ---- prologue: x chunk into buf3 ----
    if (use_frag_x) {
        GLL(xdec8 + ((size_t)(bm * 4 + skc) * 2 + spl) * 64 + l,
            smem + 3 * 8192 + dslot);
    } else {
        // convert raw fp32 x (32 rows x 64 cols) to hi/lo frags
        const int xr = tid >> 4;            // 0..31
        const int c4 = (tid & 15) * 4;      // 0..60
        const float* xp = xraw + (size_t)(row0 + xr) * (Tq * Fq) + c4;
        f32x4 v = *(const f32x4*)xp;
        bf16x4 hv, lv;
#pragma unroll
        for (int e = 0; e < 4; ++e) {
            __bf16 a = (__bf16)v[e];
            hv[e] = a;
            lv[e] = (__bf16)(v[e] - (float)a);
        }
        const int kco = c4 >> 4;
        const int lnx = xr + 32 * ((c4 >> 3) & 1);
        const int eo  = (c4 & 7) * 2;
        char* xb = smem + 3 * 8192 + (kco * 2) * 1024 + lnx * 16 + eo;
        *(bf16x4*)xb          = hv;
        *(bf16x4*)(xb + 1024) = lv;
        asm volatile("s_waitcnt vmcnt(0)" ::: "memory");   // reset vm counting
    }
    // ---- prologue: h chunks 0,1 + B(0),B(1) ----
    STAGE_H(0, 0);
    STAGE_H(1, 1);
    LOADB(0, 0);
    LOADB(1, 1);
    BARV(4);   // x, G0, G1, B0 complete; B1 (4 ops) in flight

    // ---- pipelined K loop: 17 chunks (0..15 = h, 16 = x) ----
#pragma unroll
    for (int i = 0; i < 17; ++i) {
        if (i <= 13) STAGE_H(i + 2, (i + 2) % 3);
        if (i <= 14) LOADB((i + 2) % 3, i + 2);
        COMPUTE(i == 16 ? 3 : i % 3, i % 3);
        if (i <= 13)      BARV(5);   // leaves G(i+2)+B(i+2)
        else if (i == 14) BARV(4);   // leaves B(16)
        else if (i == 15) BARV(0);   // drain all before x-chunk compute
    }
    BARL();   // fragment reads retired; smem becomes zsd

    // ---- epilogue: K-half reduce + gates + state update (single pass) ----
    // C frag: col(unit) = l&31, row = (r&3) + 8*(r>>2) + 4*(l>>5)
#pragma unroll
    for (int r = 0; r < 16; ++r) {
        const int rowi = (r & 3) + 8 * (r >> 2) + 4 * (l >> 5);
        zsd[kh][g][rowi][l & 31] = acc[r];
    }
    __syncthreads();
    {
        const int row = tid >> 4;          // 0..31
        const int uu  = (tid & 15) * 2;    // 0..30
        const int grow = row0 + row;
        const int gu   = bu * 32 + uu;
        const size_t gidx = (size_t)grow * Uq + gu;
        float z[4][2];
#pragma unroll
        for (int gg = 0; gg < 4; ++gg)
#pragma unroll
            for (int j = 0; j < 2; ++j)
                z[gg][j] = zsd[0][gg][row][uu + j] + zsd[1][gg][row][uu + j];
        f32x2 bi  = *(const f32x2*)(bias + 0 * Uq + gu);
        f32x2 bf2 = *(const f32x2*)(bias + 1 * Uq + gu);
        f32x2 bg2 = *(const f32x2*)(bias + 2 * Uq + gu);
        f32x2 bo2 = *(const f32x2*)(bias + 3 * Uq + gu);
        f32x2 cv = *(const f32x2*)(c_st + gidx);
        float hval[2];
#pragma unroll
        for (int j = 0; j < 2; ++j) {
            float vi = sigmoidf_(z[0][j] + bi[j]);
            float vf = sigmoidf_(z[1][j] + bf2[j]);
            float vg = tanhf_  (z[2][j] + bg2[j]);
            float vo = sigmoidf_(z[3][j] + bo2[j]);
            float cn = vf * cv[j] + vi * vg;
            cv[j] = cn;
            hval[j] = vo * tanhf_(cn);
        }
        *(f32x2*)(c_st + gidx) = cv;
        // h-frag write (r7-verified): mt = grow>>5 = bm, kcw = gu>>4,
        // lane = row + 32*((uu>>3)&1), elem = uu&7
        const int kcw = bu * 2 + (uu >> 4);
        const int lnw = row + 32 * ((uu >> 3) & 1);
        const int e   = uu & 7;
        bf16x2 hh, hl;
        __bf16 a0b = (__bf16)hval[0];
        hh[0] = a0b; hl[0] = (__bf16)(hval[0] - (float)a0b);
        __bf16 a1b = (__bf16)hval[1];
        hh[1] = a1b; hl[1] = (__bf16)(hval[1] - (float)a1b);
        char* base = (char*)apw + ((size_t)(bm * 64 + kcw) * 2) * 1024 + lnw * 16 + e * 2;
        *(bf16x2*)(base)        = hh;   // pl0 (hi)
        *(bf16x2*)(base + 1024) = hl;   // pl1 (lo)
    }
#undef STAGE_H
#undef LOADB
#undef COMPUTE
}

// ---------------------------------------------------------------------------
// Dense readout from h-fragments: p = h @ Wd + bd; writes out[:, step, :] AND
// the next step's x-fragments (hi/lo). (r7/r8-verified)
// ---------------------------------------------------------------------------
__global__ __launch_bounds__(256)
void readout(const bf16x8* __restrict__ ap, const float* __restrict__ Wd,
             const float* __restrict__ bd, float* __restrict__ out,
             __bf16* __restrict__ Xdec, int step)
{
    __shared__ float red[2][4][64];
    const int t = threadIdx.x;
    const int f = t & 63, kg = t >> 6;
    const int r0 = (int)blockIdx.x * 2;
    const int mt = r0 >> 5;
    const int l0 = r0 & 31;
    const bf16x8* base = ap + (size_t)mt * 8192;
    float s0 = 0.0f, s1 = 0.0f;
#pragma unroll 4
    for (int kc = kg * 16; kc < kg * 16 + 16; ++kc) {
#pragma unroll
        for (int hl = 0; hl < 2; ++hl) {
            bf16x8 h0h = base[(size_t)kc * 128 + hl * 32 + l0];
            bf16x8 h0l = base[(size_t)kc * 128 + 64 + hl * 32 + l0];
            bf16x8 h1h = base[(size_t)kc * 128 + hl * 32 + l0 + 1];
            bf16x8 h1l = base[(size_t)kc * 128 + 64 + hl * 32 + l0 + 1];
            const float* wp = Wd + ((size_t)kc * 16 + hl * 8) * Fq + f;
#pragma unroll
            for (int e = 0; e < 8; ++e) {
                float wv = wp[(size_t)e * Fq];
                s0 = fmaf((float)h0h[e] + (float)h0l[e], wv, s0);
                s1 = fmaf((float)h1h[e] + (float)h1l[e], wv, s1);
            }
        }
    }
    red[0][kg][f] = s0;
    red[1][kg][f] = s1;
    __syncthreads();
    if (t < 128) {
        const int rr = t >> 6, f2 = t & 63;
        const int row2 = r0 + rr;
        float sum = red[rr][0][f2] + red[rr][1][f2] + red[rr][2][f2] + red[rr][3][f2] + bd[f2];
        out[((size_t)row2 * OSTEPS + step) * Fq + f2] = sum;
        __bf16 hi = (__bf16)sum;
        __bf16 lo = (__bf16)(sum - (float)hi);
        const int kc4 = f2 >> 4;
        const int ln2 = (row2 & 31) + 32 * ((f2 >> 3) & 1);
        const int e2  = f2 & 7;
        size_t b0 = ((size_t)(mt * 4 + kc4) * 2) * 512 + (size_t)ln2 * 8 + e2;  // bf16 units
        Xdec[b0]       = hi;
        Xdec[b0 + 512] = lo;
    }
}

__global__ void zero_ws(f32x4* __restrict__ a, int n) {
    int i = blockIdx.x * 256 + threadIdx.x;
    f32x4 z = {0.0f, 0.0f, 0.0f, 0.0f};
    if (i < n) a[i] = z;
}

extern "C" void kernel_launch(void* const* d_in, const int* in_sizes, int n_in,
                              void* d_out, int out_size, void* d_ws, size_t ws_size,
                              hipStream_t stream) {
    const float* inputs = (const float*)d_in[0];  // [512][128][64]
    const float* Wx     = (const float*)d_in[1];  // [64][4096]
    const float* Wh     = (const float*)d_in[2];  // [1024][4096]
    const float* b      = (const float*)d_in[3];  // [4096]
    const float* Wd     = (const float*)d_in[4];  // [1024][64]
    const float* bd     = (const float*)d_in[5];  // [64]
    float* out = (float*)d_out;

    // ws (bytes): c 0 | ap0 2MB | ap1 4MB | Xdec 6MB | BpH | BpL  (~24.3 MB)
    char* ws = (char*)d_ws;
    float*  c_st = (float*)ws;
    bf16x8* ap0  = (bf16x8*)(ws + 2097152);
    bf16x8* ap1  = (bf16x8*)(ws + 4194304);
    __bf16* Xdec = (__bf16*)(ws + 6291456);
    bf16x8* BpH  = (bf16x8*)(ws + 6291456 + 131072);
    bf16x8* BpL  = BpH + (size_t)128 * NKC16 * 64;

    pack_w<<<2176, 256, 0, stream>>>(Wh, Wx, BpH, BpL);
    zero_ws<<<1024, 256, 0, stream>>>((f32x4*)ws, 262144);   // c + ap0 (4 MB)

    bf16x8* apc = ap0;
    bf16x8* apn = ap1;
    for (int t = 0; t < Tq + OSTEPS - 1; ++t) {
        const int use_frag_x = (t >= Tq) ? 1 : 0;
        const float* xr = inputs + (size_t)t * Fq;   // valid for t < 128; unused after
        lstm_step<<<512, 512, 0, stream>>>(apc, xr, (const bf16x8*)Xdec, use_frag_x,
                                           BpH, BpL, b, apn, c_st);
        bf16x8* tmp = apc; apc = apn; apn = tmp;
        if (t >= Tq - 1)
            readout<<<256, 256, 0, stream>>>(apc, Wd, bd, out, Xdec, t - (Tq - 1));
    }
}

// Round 11
// 2350.874 us; speedup vs baseline: 1.4073x; 1.4073x over previous
//
#include <hip/hip_runtime.h>
#include <math.h>

#define Bq 512
#define Tq 128
#define Fq 64
#define Uq 1024
#define OSTEPS 24
#define NKC16 68

typedef __bf16 bf16x8 __attribute__((ext_vector_type(8)));
typedef __bf16 bf16x4 __attribute__((ext_vector_type(4)));
typedef __bf16 bf16x2 __attribute__((ext_vector_type(2)));
typedef float f32x16 __attribute__((ext_vector_type(16)));
typedef float f32x4 __attribute__((ext_vector_type(4)));
typedef float f32x2 __attribute__((ext_vector_type(2)));

__device__ __forceinline__ float sigmoidf_(float x) {
    return 1.0f / (1.0f + __expf(-x));
}
__device__ __forceinline__ float tanhf_(float x) {
    return 2.0f / (1.0f + __expf(-2.0f * x)) - 1.0f;
}

// barrier WITHOUT vmcnt drain: LDS-complete + hw barrier; global loads stay in flight
#define BAR() do {                                             \
    asm volatile("s_waitcnt lgkmcnt(0)" ::: "memory");         \
    __builtin_amdgcn_s_barrier();                              \
} while (0)

// ---------------------------------------------------------------------------
// Pack Wh [1024][4096] + Wx [64][4096] (fp32, z-col = g*1024+u) into B-fragment
// order for v_mfma_f32_32x32x16_bf16, single bf16 (hi) plane.
// Bp[(gcol32*68 + kc16)*64 + lane]: gcol32 = g*32 + ublk; col = lane&31;
// k = kc16*16 + (lane>>5)*8 + j  (k<1024 -> Wh; else Wx row k-1024)
// ---------------------------------------------------------------------------
__global__ __launch_bounds__(256)
void pack_w(const float* __restrict__ Wh, const float* __restrict__ Wx,
            bf16x8* __restrict__ BpH)
{
    long id = (long)blockIdx.x * 256 + threadIdx.x;   // 128*68*64 slots
    int lane = (int)(id & 63);
    long rest = id >> 6;
    int kc16 = (int)(rest % NKC16);
    int gcol = (int)(rest / NKC16);                   // 0..127
    int col = (gcol >> 5) * Uq + (gcol & 31) * 32 + (lane & 31);
    int k0 = kc16 * 16 + (lane >> 5) * 8;
    bf16x8 hv;
#pragma unroll
    for (int j = 0; j < 8; ++j) {
        int k = k0 + j;
        float v = (k < Uq) ? Wh[(size_t)k * (4 * Uq) + col]
                           : Wx[(size_t)(k - Uq) * (4 * Uq) + col];
        hv[j] = (__bf16)v;
    }
    BpH[id] = hv;
}

// ---------------------------------------------------------------------------
// Fused LSTM step, MFMA bf16x2 split (h hi/lo x W hi), software-pipelined
// (depth-2 prefetch, no-vmcnt-drain barriers, fully unrolled 17-chunk K loop).
// Block: 64 batch rows x 32 units, 512 threads = 8 waves.
// Wave role: gate-pair gp = w&1 (gates 2gp,2gp+1), K-quarter kq = w>>1.
// Each wave: acc[2 gates][2 mh] 32x32 tiles, partial over its K-quarter.
// Grid: 256 = 8 bm x 32 bu.   (r5 structure, verified at 2822 us)
// ---------------------------------------------------------------------------
#define STAGE_LOAD(c, j) do {                                                   \
    if ((c) < 16) {                                                             \
        ash[j] = *(const bf16x8*)(hrow_hi + (c) * 64);                          \
        asl[j] = *(const bf16x8*)(hrow_lo + (c) * 64);                          \
    } else {                                                                    \
        f32x4 v0_ = *(const f32x4*)xrow;                                        \
        f32x4 v1_ = *(const f32x4*)(xrow + 4);                                  \
        bf16x8 hv_, lv_;                                                        \
        _Pragma("unroll")                                                       \
        for (int j_ = 0; j_ < 4; ++j_) { float v = v0_[j_]; __bf16 h_ = (__bf16)v; \
            hv_[j_] = h_; lv_[j_] = (__bf16)(v - (float)h_); }                  \
        _Pragma("unroll")                                                       \
        for (int j_ = 0; j_ < 4; ++j_) { float v = v1_[j_]; __bf16 h_ = (__bf16)v; \
            hv_[4 + j_] = h_; lv_[4 + j_] = (__bf16)(v - (float)h_); }          \
        ash[j] = hv_; asl[j] = lv_;                                             \
    }                                                                           \
} while (0)

#define STAGE_WRITE(nb, j) do {                                                 \
    As2[nb][0][smh][sslot] = ash[j];                                            \
    As2[nb][1][smh][sslot] = asl[j];                                            \
} while (0)

#define LOADB(s, c) do {                                                        \
    Bh[s][0] = bpH0[((c) * 4 + kq) * 64];                                       \
    Bh[s][1] = bpH1[((c) * 4 + kq) * 64];                                       \
} while (0)

#define COMPUTE(cb, si) do {                                                    \
    bf16x8 ah0_ = As2[cb][0][0][rdslot];                                        \
    bf16x8 al0_ = As2[cb][1][0][rdslot];                                        \
    bf16x8 ah1_ = As2[cb][0][1][rdslot];                                        \
    bf16x8 al1_ = As2[cb][1][1][rdslot];                                        \
    __builtin_amdgcn_s_setprio(1);                                              \
    _Pragma("unroll")                                                           \
    for (int g2_ = 0; g2_ < 2; ++g2_) {                                         \
        acc[g2_][0] = __builtin_amdgcn_mfma_f32_32x32x16_bf16(ah0_, Bh[si][g2_], acc[g2_][0], 0, 0, 0); \
        acc[g2_][0] = __builtin_amdgcn_mfma_f32_32x32x16_bf16(al0_, Bh[si][g2_], acc[g2_][0], 0, 0, 0); \
        acc[g2_][1] = __builtin_amdgcn_mfma_f32_32x32x16_bf16(ah1_, Bh[si][g2_], acc[g2_][1], 0, 0, 0); \
        acc[g2_][1] = __builtin_amdgcn_mfma_f32_32x32x16_bf16(al1_, Bh[si][g2_], acc[g2_][1], 0, 0, 0); \
    }                                                                           \
    __builtin_amdgcn_s_setprio(0);                                              \
} while (0)

__global__ __launch_bounds__(512, 2)
void lstm_step(const __bf16* __restrict__ hhi_in,   // [512][1024]
               const __bf16* __restrict__ hlo_in,
               const float* __restrict__ xsrc,      // fp32, 64 cols, stride xstride
               long xstride,
               const bf16x8* __restrict__ BpH,
               const float* __restrict__ bias,      // [4096]
               __bf16* __restrict__ hhi_out,
               __bf16* __restrict__ hlo_out,
               float* __restrict__ c_st)            // [512][1024] fp32 in/out
{
    // union: A-staging frags (32 KB) then gate-exchange zsd (72 KB)
    __shared__ __align__(16) char smem[4 * 4 * 32 * 36 * 4];
    bf16x8 (*As2)[2][2][256] = (bf16x8 (*)[2][2][256])smem;   // [buf][plane][mh][slot]
    float (*zsd)[4][32][36] = (float (*)[4][32][36])smem;     // [kq][g][row][col]

    const int tid = threadIdx.x;
    const int l   = tid & 63;
    const int w   = tid >> 6;
    const int gp  = w & 1;          // gate pair: gates 2gp, 2gp+1
    const int kq  = w >> 1;         // K-quarter 0..3
    const int bm  = (int)blockIdx.x >> 5;
    const int bu  = (int)blockIdx.x & 31;
    const int row0 = bm * 64;

    // staging decomposition: 64 rows x 8 k-octets (identical to verified r3/r5)
    const int srow = tid >> 3;      // 0..63
    const int kg8  = tid & 7;       // 0..7
    const int smh  = srow >> 5;
    const int sr31 = srow & 31;
    const int sslot = sr31 * 8 + (kg8 ^ (sr31 & 7));

    // fragment read slot (kc = kq), loop-invariant
    const int rdslot = (l & 31) * 8 + ((kq * 2 + (l >> 5)) ^ (l & 7));

    // per-wave global base pointers
    const bf16x8* bpH0 = BpH + ((size_t)((gp * 2 + 0) * 32 + bu) * NKC16) * 64 + l;
    const bf16x8* bpH1 = BpH + ((size_t)((gp * 2 + 1) * 32 + bu) * NKC16) * 64 + l;
    const __bf16* hrow_hi = hhi_in + (size_t)(row0 + srow) * Uq + kg8 * 8;
    const __bf16* hrow_lo = hlo_in + (size_t)(row0 + srow) * Uq + kg8 * 8;
    const float*  xrow    = xsrc + (size_t)(row0 + srow) * xstride + kg8 * 8;

    f32x16 acc[2][2];
#pragma unroll
    for (int i = 0; i < 16; ++i) {
        acc[0][0][i] = 0.0f; acc[0][1][i] = 0.0f;
        acc[1][0][i] = 0.0f; acc[1][1][i] = 0.0f;
    }

    bf16x8 Bh[3][2];
    bf16x8 ash[2], asl[2];

    // ---- prologue ----
    STAGE_LOAD(0, 0);
    STAGE_LOAD(1, 1);
    LOADB(0, 0);
    LOADB(1, 1);
    STAGE_WRITE(0, 0);
    BAR();

    // ---- fully-unrolled pipelined K loop: 17 chunks ----
#pragma unroll
    for (int i = 0; i < 17; ++i) {
        if (i <= 14) {
            LOADB((i + 2) % 3, i + 2);
            STAGE_LOAD(i + 2, i & 1);        // (i+2)&1 == i&1
        }
        if (i <= 15) STAGE_WRITE((i + 1) & 1, (i + 1) & 1);
        COMPUTE(i & 1, i % 3);
        if (i < 16) BAR();
    }

    BAR();   // all fragment reads retired; smem becomes zsd

    // ---- epilogue: two passes over M-halves ----
#pragma unroll
    for (int mh = 0; mh < 2; ++mh) {
        // write partials: zsd[kq][gate][row][unit]
#pragma unroll
        for (int g2 = 0; g2 < 2; ++g2)
#pragma unroll
            for (int r = 0; r < 16; ++r) {
                int rowi = (r & 3) + 8 * (r >> 2) + 4 * (l >> 5);
                zsd[kq][gp * 2 + g2][rowi][l & 31] = acc[g2][mh][r];
            }
        BAR();
        // reduce 4 K-quarters + gates + state update (32 rows x 32 units)
        {
            const int row = tid >> 4;          // 0..31
            const int uu  = (tid & 15) * 2;    // 0..30
            const int grow = row0 + mh * 32 + row;
            const int gu   = bu * 32 + uu;
            const size_t gidx = (size_t)grow * Uq + gu;
            float z[4][2];
#pragma unroll
            for (int g = 0; g < 4; ++g) {
#pragma unroll
                for (int j = 0; j < 2; ++j)
                    z[g][j] = zsd[0][g][row][uu + j] + zsd[1][g][row][uu + j]
                            + zsd[2][g][row][uu + j] + zsd[3][g][row][uu + j];
            }
            f32x2 cv = *(const f32x2*)(c_st + gidx);
            bf16x2 hh, hl2;
#pragma unroll
            for (int j = 0; j < 2; ++j) {
                float vi = sigmoidf_(z[0][j] + bias[0 * Uq + gu + j]);
                float vf = sigmoidf_(z[1][j] + bias[1 * Uq + gu + j]);
                float vg = tanhf_  (z[2][j] + bias[2 * Uq + gu + j]);
                float vo = sigmoidf_(z[3][j] + bias[3 * Uq + gu + j]);
                float cn = vf * cv[j] + vi * vg;
                cv[j] = cn;
                float hval = vo * tanhf_(cn);
                __bf16 h_ = (__bf16)hval;
                hh[j] = h_;
                hl2[j] = (__bf16)(hval - (float)h_);
            }
            *(f32x2*)(c_st + gidx) = cv;
            *(bf16x2*)(hhi_out + gidx) = hh;
            *(bf16x2*)(hlo_out + gidx) = hl2;
        }
        if (mh == 0) BAR();   // pass-1 reads done before pass-2 overwrites zsd
    }
}

// ---------------------------------------------------------------------------
// Dense readout p = (hhi+hlo) @ Wd + bd ; scatter into out[:, step, :].
// (r5-verified)
// ---------------------------------------------------------------------------
__global__ __launch_bounds__(256)
void readout(const __bf16* __restrict__ hhi, const __bf16* __restrict__ hlo,
             const float* __restrict__ Wd, const float* __restrict__ bd,
             float* __restrict__ p, float* __restrict__ out, int step)
{
    __shared__ float red[2][4][64];
    const int t = threadIdx.x;
    const int f = t & 63, kq = t >> 6;
    const int r0 = blockIdx.x * 2;
    float s0 = 0.0f, s1 = 0.0f;
    const __bf16* h0h = hhi + (size_t)r0 * Uq + kq * 256;
    const __bf16* h0l = hlo + (size_t)r0 * Uq + kq * 256;
    const float* wp = Wd + (size_t)kq * 256 * Fq + f;
#pragma unroll 4
    for (int i = 0; i < 32; ++i) {
        bf16x8 ah = *(const bf16x8*)(h0h + i * 8);
        bf16x8 al = *(const bf16x8*)(h0l + i * 8);
        bf16x8 bh = *(const bf16x8*)(h0h + Uq + i * 8);
        bf16x8 bl = *(const bf16x8*)(h0l + Uq + i * 8);
#pragma unroll
        for (int j = 0; j < 8; ++j) {
            float wv = wp[(size_t)(i * 8 + j) * Fq];
            s0 = fmaf((float)ah[j] + (float)al[j], wv, s0);
            s1 = fmaf((float)bh[j] + (float)bl[j], wv, s1);
        }
    }
    red[0][kq][f] = s0;
    red[1][kq][f] = s1;
    __syncthreads();
    if (t < 128) {
        int rr = t >> 6, ff = t & 63;
        float s = red[rr][0][ff] + red[rr][1][ff] + red[rr][2][ff] + red[rr][3][ff] + bd[ff];
        p[(size_t)(r0 + rr) * Fq + ff] = s;
        out[((size_t)(r0 + rr) * OSTEPS + step) * Fq + ff] = s;
    }
}

__global__ void zero_ws(f32x4* __restrict__ a, int n) {
    int i = blockIdx.x * 256 + threadIdx.x;
    f32x4 z = {0.0f, 0.0f, 0.0f, 0.0f};
    if (i < n) a[i] = z;
}

extern "C" void kernel_launch(void* const* d_in, const int* in_sizes, int n_in,
                              void* d_out, int out_size, void* d_ws, size_t ws_size,
                              hipStream_t stream) {
    const float* inputs = (const float*)d_in[0];  // [512][128][64]
    const float* Wx     = (const float*)d_in[1];  // [64][4096]
    const float* Wh     = (const float*)d_in[2];  // [1024][4096]
    const float* b      = (const float*)d_in[3];  // [4096]
    const float* Wd     = (const float*)d_in[4];  // [1024][64]
    const float* bd     = (const float*)d_in[5];  // [64]
    float* out = (float*)d_out;

    // workspace layout: c | Hhi0 | Hlo0 | Hhi1 | Hlo1 | p | BpH  (~15.2 MB)
    float* ws = (float*)d_ws;
    float* c_st = ws;                              // 512*1024 f32 (2 MB)
    __bf16* Hhi0 = (__bf16*)(ws + Bq * Uq);        // 1 MB each
    __bf16* Hlo0 = Hhi0 + Bq * Uq;
    __bf16* Hhi1 = Hlo0 + Bq * Uq;
    __bf16* Hlo1 = Hhi1 + Bq * Uq;
    float* p = (float*)(Hlo1 + Bq * Uq);           // 512*64 f32
    bf16x8* BpH = (bf16x8*)(p + Bq * Fq);          // 557056 * 16 B = 8.9 MB

    pack_w<<<2176, 256, 0, stream>>>(Wh, Wx, BpH);
    // zero c + Hhi0 + Hlo0 (contiguous 4 MB)
    zero_ws<<<1024, 256, 0, stream>>>((f32x4*)ws, 262144);

    __bf16 *hhi_c = Hhi0, *hlo_c = Hlo0, *hhi_n = Hhi1, *hlo_n = Hlo1;
    // ---- warmup over T timesteps ----
    for (int t = 0; t < Tq; ++t) {
        lstm_step<<<256, 512, 0, stream>>>(hhi_c, hlo_c,
                                           inputs + (size_t)t * Fq, (long)Tq * Fq,
                                           BpH, b, hhi_n, hlo_n, c_st);
        __bf16* tmp;
        tmp = hhi_c; hhi_c = hhi_n; hhi_n = tmp;
        tmp = hlo_c; hlo_c = hlo_n; hlo_n = tmp;
    }
    readout<<<Bq / 2, 256, 0, stream>>>(hhi_c, hlo_c, Wd, bd, p, out, 0);
    // ---- autoregressive decode ----
    for (int s = 1; s < OSTEPS; ++s) {
        lstm_step<<<256, 512, 0, stream>>>(hhi_c, hlo_c, p, (long)Fq,
                                           BpH, b, hhi_n, hlo_n, c_st);
        __bf16* tmp;
        tmp = hhi_c; hhi_c = hhi_n; hhi_n = tmp;
        tmp = hlo_c; hlo_c = hlo_n; hlo_n = tmp;
        readout<<<Bq / 2, 256, 0, stream>>>(hhi_c, hlo_c, Wd, bd, p, out, s);
    }
}